// Round 1
// baseline (467.884 us; speedup 1.0000x reference)
//
#include <hip/hip_runtime.h>
#include <math.h>

#define N 8192
#define NV4 (N / 4)             // float4 columns
#define ROWS_PER_BLOCK 128
#define THREADS 256

// ws layout (floats):
//   deg/dinv : [0, N)
//   g        : [N, 3N)      g[b*N + r] = dinv[r] * x[b*N + r]
//   t        : [3N, 5N)     t[b*N + c] = sum_r DSM[r,c]*g[b,r]
//   msum     : [5N, 5N+2)   per-batch sum of h3 over columns

__global__ void k_colsum(const float* __restrict__ dsm, float* __restrict__ deg) {
    int c4 = blockIdx.x * THREADS + threadIdx.x;    // float4 column index
    int r0 = blockIdx.y * ROWS_PER_BLOCK;
    const float4* p = (const float4*)dsm;
    float4 acc = {0.f, 0.f, 0.f, 0.f};
    for (int i = 0; i < ROWS_PER_BLOCK; ++i) {
        float4 v = p[(size_t)(r0 + i) * NV4 + c4];
        acc.x += v.x; acc.y += v.y; acc.z += v.z; acc.w += v.w;
    }
    int c = c4 * 4;
    atomicAdd(&deg[c + 0], acc.x);
    atomicAdd(&deg[c + 1], acc.y);
    atomicAdd(&deg[c + 2], acc.z);
    atomicAdd(&deg[c + 3], acc.w);
}

__global__ void k_prep(const float* __restrict__ x, float* __restrict__ deg,
                       float* __restrict__ g) {
    int r = blockIdx.x * THREADS + threadIdx.x;
    float d = deg[r];
    float di = d > 0.f ? rsqrtf(d) : 0.f;
    deg[r] = di;                 // deg now holds dinv
    g[r]     = di * x[r];        // batch 0
    g[N + r] = di * x[N + r];    // batch 1
}

__global__ void k_matvec(const float* __restrict__ dsm, const float* __restrict__ g,
                         float* __restrict__ t) {
    __shared__ float sg0[ROWS_PER_BLOCK];
    __shared__ float sg1[ROWS_PER_BLOCK];
    int r0 = blockIdx.y * ROWS_PER_BLOCK;
    if (threadIdx.x < ROWS_PER_BLOCK) {
        sg0[threadIdx.x] = g[r0 + threadIdx.x];
        sg1[threadIdx.x] = g[N + r0 + threadIdx.x];
    }
    __syncthreads();
    int c4 = blockIdx.x * THREADS + threadIdx.x;
    const float4* p = (const float4*)dsm;
    float4 a0 = {0.f, 0.f, 0.f, 0.f};
    float4 a1 = {0.f, 0.f, 0.f, 0.f};
    for (int i = 0; i < ROWS_PER_BLOCK; ++i) {
        float4 v = p[(size_t)(r0 + i) * NV4 + c4];
        float g0 = sg0[i], g1 = sg1[i];
        a0.x += v.x * g0; a0.y += v.y * g0; a0.z += v.z * g0; a0.w += v.w * g0;
        a1.x += v.x * g1; a1.y += v.y * g1; a1.z += v.z * g1; a1.w += v.w * g1;
    }
    int c = c4 * 4;
    atomicAdd(&t[c + 0], a0.x);
    atomicAdd(&t[c + 1], a0.y);
    atomicAdd(&t[c + 2], a0.z);
    atomicAdd(&t[c + 3], a0.w);
    atomicAdd(&t[N + c + 0], a1.x);
    atomicAdd(&t[N + c + 1], a1.y);
    atomicAdd(&t[N + c + 2], a1.z);
    atomicAdd(&t[N + c + 3], a1.w);
}

__global__ void k_head(const float* __restrict__ t, const float* __restrict__ dinv,
                       const float* __restrict__ w1, const float* __restrict__ b1,
                       const float* __restrict__ lw1, const float* __restrict__ lb1,
                       const float* __restrict__ lw2, const float* __restrict__ lb2,
                       float* __restrict__ msum) {
    int c = blockIdx.x * THREADS + threadIdx.x;
    float W1 = w1[0], B1 = b1[0];
    float LW1 = lw1[0], LB1 = lb1[0];
    float LW2 = lw2[0], LB2 = lb2[0];
    float di = dinv[c];
    float v[2];
    for (int b = 0; b < 2; ++b) {
        float h = W1 * di * t[b * N + c] + B1;
        h = fmaxf(h, 0.f);
        h = fmaxf(h * LW1 + LB1, 0.f);
        h = fmaxf(h * LW2 + LB2, 0.f);
        v[b] = h;
    }
    // wave-64 shuffle reduction, then one atomic per wave per batch
    float v0 = v[0], v1 = v[1];
    for (int off = 32; off > 0; off >>= 1) {
        v0 += __shfl_down(v0, off);
        v1 += __shfl_down(v1, off);
    }
    if ((threadIdx.x & 63) == 0) {
        atomicAdd(&msum[0], v0);
        atomicAdd(&msum[1], v1);
    }
}

__global__ void k_out(const float* __restrict__ msum,
                      const float* __restrict__ w2, const float* __restrict__ b2,
                      const float* __restrict__ w3, const float* __restrict__ b3,
                      const float* __restrict__ wv, const float* __restrict__ bv,
                      float* __restrict__ out) {
    int i = blockIdx.x * THREADS + threadIdx.x;
    if (i < 2 * N) {
        // softmax over a singleton axis is identically 1.0
        out[i] = 1.0f;
    } else if (i == 2 * N) {
        float vmax = -INFINITY;
        for (int b = 0; b < 2; ++b) {
            float m = msum[b] * (1.0f / (float)N);
            float s = fmaxf(m * w2[0] + b2[0], 0.f);
            s = fmaxf(s * w3[0] + b3[0], 0.f);
            vmax = fmaxf(vmax, s);
        }
        out[2 * N] = vmax * wv[0] + bv[0];
    }
}

extern "C" void kernel_launch(void* const* d_in, const int* in_sizes, int n_in,
                              void* d_out, int out_size, void* d_ws, size_t ws_size,
                              hipStream_t stream) {
    const float* x   = (const float*)d_in[0];
    const float* dsm = (const float*)d_in[1];
    const float* w1  = (const float*)d_in[2];
    const float* b1  = (const float*)d_in[3];
    const float* lw1 = (const float*)d_in[4];
    const float* lb1 = (const float*)d_in[5];
    const float* lw2 = (const float*)d_in[6];
    const float* lb2 = (const float*)d_in[7];
    const float* w2  = (const float*)d_in[8];
    const float* b2  = (const float*)d_in[9];
    const float* w3  = (const float*)d_in[10];
    const float* b3  = (const float*)d_in[11];
    // d_in[12..13] = wa, ba (unused: softmax over singleton axis == 1.0)
    const float* wv  = (const float*)d_in[14];
    const float* bv  = (const float*)d_in[15];

    float* ws   = (float*)d_ws;
    float* deg  = ws;            // becomes dinv after k_prep
    float* g    = ws + N;
    float* t    = ws + 3 * N;
    float* msum = ws + 5 * N;

    // zero accumulators (ws is poisoned before every launch)
    hipMemsetAsync(deg, 0, N * sizeof(float), stream);
    hipMemsetAsync(t, 0, (2 * N + 2) * sizeof(float), stream);  // t + msum contiguous

    dim3 big(NV4 / THREADS, N / ROWS_PER_BLOCK);  // (8, 64) = 512 blocks
    k_colsum<<<big, THREADS, 0, stream>>>(dsm, deg);
    k_prep<<<N / THREADS, THREADS, 0, stream>>>(x, deg, g);
    k_matvec<<<big, THREADS, 0, stream>>>(dsm, g, t);
    k_head<<<N / THREADS, THREADS, 0, stream>>>(t, deg, w1, b1, lw1, lb1, lw2, lb2, msum);
    k_out<<<(2 * N + 1 + THREADS - 1) / THREADS, THREADS, 0, stream>>>(
        msum, w2, b2, w3, b3, wv, bv, (float*)d_out);
}

// Round 2
// 443.686 us; speedup vs baseline: 1.0545x; 1.0545x over previous
//
#include <hip/hip_runtime.h>
#include <math.h>

#define N 8192
#define NV4 (N / 4)             // float4 columns per row
#define ROWS_PER_BLOCK 64
#define GRID_X 8                // NV4 / THREADS
#define THREADS 256

// ws layout (floats):
//   deg  : [0, N)        raw column sums of DSM (dinv computed inline by consumers)
//   t    : [N, 3N)       t[b*N + c] = sum_r DSM[r,c] * dinv[r] * x[b*N + r]
//   msum : [3N, 3N+2)    per-batch sum of h3 over columns

__global__ void k_colsum(const float* __restrict__ dsm, float* __restrict__ deg) {
    // swizzle column-chunk so concurrent blocks hit different column phases
    int chunk = (blockIdx.x + blockIdx.y) & (GRID_X - 1);
    int c4 = chunk * THREADS + threadIdx.x;
    int r0 = blockIdx.y * ROWS_PER_BLOCK;
    const float4* p = (const float4*)dsm;
    float4 acc = {0.f, 0.f, 0.f, 0.f};
#pragma unroll 8
    for (int i = 0; i < ROWS_PER_BLOCK; ++i) {
        float4 v = p[(size_t)(r0 + i) * NV4 + c4];
        acc.x += v.x; acc.y += v.y; acc.z += v.z; acc.w += v.w;
    }
    int c = c4 * 4;
    atomicAdd(&deg[c + 0], acc.x);
    atomicAdd(&deg[c + 1], acc.y);
    atomicAdd(&deg[c + 2], acc.z);
    atomicAdd(&deg[c + 3], acc.w);
}

__global__ void k_matvec(const float* __restrict__ dsm, const float* __restrict__ deg,
                         const float* __restrict__ x, float* __restrict__ t) {
    __shared__ float sg0[ROWS_PER_BLOCK];
    __shared__ float sg1[ROWS_PER_BLOCK];
    int r0 = blockIdx.y * ROWS_PER_BLOCK;
    if (threadIdx.x < ROWS_PER_BLOCK) {
        int r = r0 + threadIdx.x;
        float d = deg[r];
        float di = d > 0.f ? rsqrtf(d) : 0.f;
        sg0[threadIdx.x] = di * x[r];
        sg1[threadIdx.x] = di * x[N + r];
    }
    __syncthreads();
    int chunk = (blockIdx.x + blockIdx.y) & (GRID_X - 1);
    int c4 = chunk * THREADS + threadIdx.x;
    const float4* p = (const float4*)dsm;
    float4 a0 = {0.f, 0.f, 0.f, 0.f};
    float4 a1 = {0.f, 0.f, 0.f, 0.f};
#pragma unroll 8
    for (int i = 0; i < ROWS_PER_BLOCK; ++i) {
        float4 v = p[(size_t)(r0 + i) * NV4 + c4];
        float g0 = sg0[i], g1 = sg1[i];
        a0.x += v.x * g0; a0.y += v.y * g0; a0.z += v.z * g0; a0.w += v.w * g0;
        a1.x += v.x * g1; a1.y += v.y * g1; a1.z += v.z * g1; a1.w += v.w * g1;
    }
    int c = c4 * 4;
    atomicAdd(&t[c + 0], a0.x);
    atomicAdd(&t[c + 1], a0.y);
    atomicAdd(&t[c + 2], a0.z);
    atomicAdd(&t[c + 3], a0.w);
    atomicAdd(&t[N + c + 0], a1.x);
    atomicAdd(&t[N + c + 1], a1.y);
    atomicAdd(&t[N + c + 2], a1.z);
    atomicAdd(&t[N + c + 3], a1.w);
}

__global__ void k_head(const float* __restrict__ t, const float* __restrict__ deg,
                       const float* __restrict__ w1, const float* __restrict__ b1,
                       const float* __restrict__ lw1, const float* __restrict__ lb1,
                       const float* __restrict__ lw2, const float* __restrict__ lb2,
                       float* __restrict__ msum, float* __restrict__ out) {
    int c = blockIdx.x * THREADS + threadIdx.x;
    float W1 = w1[0], B1 = b1[0];
    float LW1 = lw1[0], LB1 = lb1[0];
    float LW2 = lw2[0], LB2 = lb2[0];
    float d = deg[c];
    float di = d > 0.f ? rsqrtf(d) : 0.f;
    float v0, v1;
    {
        float h = W1 * di * t[c] + B1;
        h = fmaxf(h, 0.f);
        h = fmaxf(h * LW1 + LB1, 0.f);
        v0 = fmaxf(h * LW2 + LB2, 0.f);
    }
    {
        float h = W1 * di * t[N + c] + B1;
        h = fmaxf(h, 0.f);
        h = fmaxf(h * LW1 + LB1, 0.f);
        v1 = fmaxf(h * LW2 + LB2, 0.f);
    }
    // softmax over singleton last axis == 1.0 exactly
    out[c] = 1.0f;
    out[N + c] = 1.0f;
    // wave-64 shuffle reduction, one atomic per wave per batch
    for (int off = 32; off > 0; off >>= 1) {
        v0 += __shfl_down(v0, off);
        v1 += __shfl_down(v1, off);
    }
    if ((threadIdx.x & 63) == 0) {
        atomicAdd(&msum[0], v0);
        atomicAdd(&msum[1], v1);
    }
}

__global__ void k_out(const float* __restrict__ msum,
                      const float* __restrict__ w2, const float* __restrict__ b2,
                      const float* __restrict__ w3, const float* __restrict__ b3,
                      const float* __restrict__ wv, const float* __restrict__ bv,
                      float* __restrict__ out) {
    float vmax = -INFINITY;
    for (int b = 0; b < 2; ++b) {
        float m = msum[b] * (1.0f / (float)N);
        float s = fmaxf(m * w2[0] + b2[0], 0.f);
        s = fmaxf(s * w3[0] + b3[0], 0.f);
        vmax = fmaxf(vmax, s);
    }
    out[2 * N] = vmax * wv[0] + bv[0];
}

extern "C" void kernel_launch(void* const* d_in, const int* in_sizes, int n_in,
                              void* d_out, int out_size, void* d_ws, size_t ws_size,
                              hipStream_t stream) {
    const float* x   = (const float*)d_in[0];
    const float* dsm = (const float*)d_in[1];
    const float* w1  = (const float*)d_in[2];
    const float* b1  = (const float*)d_in[3];
    const float* lw1 = (const float*)d_in[4];
    const float* lb1 = (const float*)d_in[5];
    const float* lw2 = (const float*)d_in[6];
    const float* lb2 = (const float*)d_in[7];
    const float* w2  = (const float*)d_in[8];
    const float* b2  = (const float*)d_in[9];
    const float* w3  = (const float*)d_in[10];
    const float* b3  = (const float*)d_in[11];
    // d_in[12..13] = wa, ba unused: softmax over singleton axis == 1.0
    const float* wv  = (const float*)d_in[14];
    const float* bv  = (const float*)d_in[15];

    float* ws   = (float*)d_ws;
    float* deg  = ws;
    float* t    = ws + N;
    float* msum = ws + 3 * N;

    // one fused zeroing of deg + t + msum (contiguous)
    hipMemsetAsync(deg, 0, (3 * N + 2) * sizeof(float), stream);

    dim3 big(GRID_X, N / ROWS_PER_BLOCK);   // (8, 128) = 1024 blocks
    k_colsum<<<big, THREADS, 0, stream>>>(dsm, deg);
    k_matvec<<<big, THREADS, 0, stream>>>(dsm, deg, x, t);
    k_head<<<N / THREADS, THREADS, 0, stream>>>(t, deg, w1, b1, lw1, lb1, lw2, lb2,
                                                msum, (float*)d_out);
    k_out<<<1, 1, 0, stream>>>(msum, w2, b2, w3, b3, wv, bv, (float*)d_out);
}

// Round 3
// 439.464 us; speedup vs baseline: 1.0647x; 1.0096x over previous
//
#include <hip/hip_runtime.h>
#include <math.h>

#define N 8192
#define NV4 (N / 4)             // float4 columns per row
#define RPB 64                  // rows per block (row-strip)
#define NBY (N / RPB)           // 128 row-strips
#define GRID_X 8                // column chunks: NV4 / THREADS
#define THREADS 256

// ws layout (floats) — every region is fully overwritten before read, so no
// zero-init is needed (poison-safe), and there are no atomics anywhere:
//   degp  : [NBY][N]      per-row-strip partial column sums      (4 MB)
//   tpart : [NBY][2][N]   per-row-strip partial matvec results   (8 MB)
//   hpart : [32][2]       per-head-block partial sums of h3
#define DEGP_OFF  0
#define TPART_OFF (NBY * N)
#define HPART_OFF (TPART_OFF + NBY * 2 * N)

__global__ void k_colsum(const float* __restrict__ dsm, float* __restrict__ degp) {
    int chunk = (blockIdx.x + blockIdx.y) & (GRID_X - 1);   // column-phase swizzle
    int c4 = chunk * THREADS + threadIdx.x;
    int r0 = blockIdx.y * RPB;
    const float4* p = (const float4*)dsm;
    float4 acc = {0.f, 0.f, 0.f, 0.f};
#pragma unroll 16
    for (int i = 0; i < RPB; ++i) {
        float4 v = p[(size_t)(r0 + i) * NV4 + c4];
        acc.x += v.x; acc.y += v.y; acc.z += v.z; acc.w += v.w;
    }
    ((float4*)(degp + (size_t)blockIdx.y * N))[c4] = acc;
}

__global__ void k_matvec(const float* __restrict__ dsm, const float* __restrict__ degp,
                         const float* __restrict__ x, float* __restrict__ tpart) {
    __shared__ float sred[4 * RPB];
    __shared__ float sg0[RPB];
    __shared__ float sg1[RPB];
    int r0 = blockIdx.y * RPB;

    // Phase A: deg[r] = sum over all 128 row-strip partials, for our 64 rows.
    {
        int rl = threadIdx.x & 63;          // row within strip
        int q  = threadIdx.x >> 6;          // quarter: 32 strips each
        const float* dp = degp + r0 + rl;
        float s = 0.f;
#pragma unroll 8
        for (int j = 0; j < 32; ++j) s += dp[(size_t)(q * 32 + j) * N];
        sred[q * RPB + rl] = s;
    }
    __syncthreads();
    if (threadIdx.x < RPB) {
        int r = threadIdx.x;
        float d = sred[r] + sred[RPB + r] + sred[2 * RPB + r] + sred[3 * RPB + r];
        float di = d > 0.f ? rsqrtf(d) : 0.f;
        sg0[r] = di * x[r0 + r];
        sg1[r] = di * x[N + r0 + r];
    }
    __syncthreads();

    // Phase B: weighted partial matvec over our 64-row strip.
    int chunk = (blockIdx.x + blockIdx.y) & (GRID_X - 1);
    int c4 = chunk * THREADS + threadIdx.x;
    const float4* p = (const float4*)dsm;
    float4 a0 = {0.f, 0.f, 0.f, 0.f};
    float4 a1 = {0.f, 0.f, 0.f, 0.f};
#pragma unroll 16
    for (int i = 0; i < RPB; ++i) {
        float4 v = p[(size_t)(r0 + i) * NV4 + c4];
        float g0 = sg0[i], g1 = sg1[i];
        a0.x += v.x * g0; a0.y += v.y * g0; a0.z += v.z * g0; a0.w += v.w * g0;
        a1.x += v.x * g1; a1.y += v.y * g1; a1.z += v.z * g1; a1.w += v.w * g1;
    }
    ((float4*)(tpart + ((size_t)blockIdx.y * 2 + 0) * N))[c4] = a0;
    ((float4*)(tpart + ((size_t)blockIdx.y * 2 + 1) * N))[c4] = a1;
}

__global__ void k_head(const float* __restrict__ degp, const float* __restrict__ tpart,
                       const float* __restrict__ w1, const float* __restrict__ b1,
                       const float* __restrict__ lw1, const float* __restrict__ lb1,
                       const float* __restrict__ lw2, const float* __restrict__ lb2,
                       float* __restrict__ hpart, float* __restrict__ out) {
    __shared__ float swred[8];   // 4 waves x 2 batches
    int c = blockIdx.x * THREADS + threadIdx.x;

    float d = 0.f, t0 = 0.f, t1 = 0.f;
#pragma unroll 8
    for (int by = 0; by < NBY; ++by) {
        d  += degp[(size_t)by * N + c];
        t0 += tpart[((size_t)by * 2 + 0) * N + c];
        t1 += tpart[((size_t)by * 2 + 1) * N + c];
    }
    float di = d > 0.f ? rsqrtf(d) : 0.f;

    float W1 = w1[0], B1 = b1[0];
    float LW1 = lw1[0], LB1 = lb1[0];
    float LW2 = lw2[0], LB2 = lb2[0];
    float h0 = fmaxf(W1 * di * t0 + B1, 0.f);
    h0 = fmaxf(h0 * LW1 + LB1, 0.f);
    h0 = fmaxf(h0 * LW2 + LB2, 0.f);
    float h1 = fmaxf(W1 * di * t1 + B1, 0.f);
    h1 = fmaxf(h1 * LW1 + LB1, 0.f);
    h1 = fmaxf(h1 * LW2 + LB2, 0.f);

    // softmax over singleton last axis == 1.0 exactly
    out[c] = 1.0f;
    out[N + c] = 1.0f;

    // block reduction: wave shuffle then LDS across 4 waves
    float v0 = h0, v1 = h1;
    for (int off = 32; off > 0; off >>= 1) {
        v0 += __shfl_down(v0, off);
        v1 += __shfl_down(v1, off);
    }
    int wave = threadIdx.x >> 6;
    if ((threadIdx.x & 63) == 0) { swred[wave] = v0; swred[4 + wave] = v1; }
    __syncthreads();
    if (threadIdx.x == 0) {
        hpart[blockIdx.x * 2 + 0] = swred[0] + swred[1] + swred[2] + swred[3];
        hpart[blockIdx.x * 2 + 1] = swred[4] + swred[5] + swred[6] + swred[7];
    }
}

__global__ void k_out(const float* __restrict__ hpart,
                      const float* __restrict__ w2, const float* __restrict__ b2,
                      const float* __restrict__ w3, const float* __restrict__ b3,
                      const float* __restrict__ wv, const float* __restrict__ bv,
                      float* __restrict__ out) {
    int tid = threadIdx.x;
    float s0 = tid < 32 ? hpart[tid * 2 + 0] : 0.f;
    float s1 = tid < 32 ? hpart[tid * 2 + 1] : 0.f;
    for (int off = 16; off > 0; off >>= 1) {
        s0 += __shfl_down(s0, off);
        s1 += __shfl_down(s1, off);
    }
    if (tid == 0) {
        float vmax = -INFINITY;
        float m0 = s0 * (1.0f / (float)N);
        float m1 = s1 * (1.0f / (float)N);
        float a = fmaxf(m0 * w2[0] + b2[0], 0.f);
        a = fmaxf(a * w3[0] + b3[0], 0.f);
        float b = fmaxf(m1 * w2[0] + b2[0], 0.f);
        b = fmaxf(b * w3[0] + b3[0], 0.f);
        vmax = fmaxf(a, b);
        out[2 * N] = vmax * wv[0] + bv[0];
    }
}

extern "C" void kernel_launch(void* const* d_in, const int* in_sizes, int n_in,
                              void* d_out, int out_size, void* d_ws, size_t ws_size,
                              hipStream_t stream) {
    const float* x   = (const float*)d_in[0];
    const float* dsm = (const float*)d_in[1];
    const float* w1  = (const float*)d_in[2];
    const float* b1  = (const float*)d_in[3];
    const float* lw1 = (const float*)d_in[4];
    const float* lb1 = (const float*)d_in[5];
    const float* lw2 = (const float*)d_in[6];
    const float* lb2 = (const float*)d_in[7];
    const float* w2  = (const float*)d_in[8];
    const float* b2  = (const float*)d_in[9];
    const float* w3  = (const float*)d_in[10];
    const float* b3  = (const float*)d_in[11];
    // d_in[12..13] = wa, ba unused: softmax over a singleton axis == 1.0
    const float* wv  = (const float*)d_in[14];
    const float* bv  = (const float*)d_in[15];

    float* ws    = (float*)d_ws;
    float* degp  = ws + DEGP_OFF;
    float* tpart = ws + TPART_OFF;
    float* hpart = ws + HPART_OFF;

    dim3 big(GRID_X, NBY);   // (8, 128) = 1024 blocks
    k_colsum<<<big, THREADS, 0, stream>>>(dsm, degp);
    k_matvec<<<big, THREADS, 0, stream>>>(dsm, degp, x, tpart);
    k_head<<<N / THREADS, THREADS, 0, stream>>>(degp, tpart, w1, b1, lw1, lb1,
                                                lw2, lb2, hpart, (float*)d_out);
    k_out<<<1, 64, 0, stream>>>(hpart, w2, b2, w3, b3, wv, bv, (float*)d_out);
}